// Round 1
// baseline (168.012 us; speedup 1.0000x reference)
//
#include <hip/hip_runtime.h>

typedef unsigned short UST;
typedef __attribute__((ext_vector_type(8))) __bf16 bf16x8;
typedef __attribute__((ext_vector_type(4))) float f32x4;

#define NB 4
#define NH 8
#define LSEQ 1024
#define DMODEL 512
#define DH 64

__device__ __forceinline__ UST f2bf(float f) {
  union { float f; unsigned u; } v; v.f = f;
  unsigned u = v.u;
  return (UST)((u + 0x7FFFu + ((u >> 16) & 1u)) >> 16);
}
__device__ __forceinline__ float bf2f(UST h) {
  union { unsigned u; float f; } v; v.u = ((unsigned)h) << 16;
  return v.f;
}

// ---------------- kernel 1: x (fp32) -> bf16 ----------------
__global__ void k_convert_x(const float* __restrict__ x, UST* __restrict__ xbf) {
  int i = blockIdx.x * 256 + threadIdx.x;   // 2097152/4 elements
  float4 v = ((const float4*)x)[i];
  ushort4 o;
  o.x = f2bf(v.x); o.y = f2bf(v.y); o.z = f2bf(v.z); o.w = f2bf(v.w);
  ((ushort4*)xbf)[i] = o;
}

// ---------------- kernel 2: W [512][1536] fp32 -> WT [1536][512] bf16 ----------------
__global__ void k_transpose_W(const float* __restrict__ W, UST* __restrict__ WT) {
  __shared__ float tile[64][65];
  int n0 = blockIdx.x * 64;   // over 1536
  int k0 = blockIdx.y * 64;   // over 512
  int tx = threadIdx.x & 63, ty = threadIdx.x >> 6;  // ty 0..3
#pragma unroll
  for (int i = 0; i < 16; ++i) {
    int k = ty + i * 4;
    tile[k][tx] = W[(size_t)(k0 + k) * 1536 + n0 + tx];
  }
  __syncthreads();
#pragma unroll
  for (int i = 0; i < 16; ++i) {
    int n = ty + i * 4;
    WT[(size_t)(n0 + n) * 512 + k0 + tx] = f2bf(tile[tx][n]);
  }
}

// ---------------- kernel 3: projection GEMM + scatter ----------------
// qext/kext: [32 bh][1024 l][128] bf16  (cols 0..63 filled here, 64..127 by k_relpos)
// vT:        [32 bh][64 d][1024 l] bf16
__global__ __launch_bounds__(256) void k_proj(
    const UST* __restrict__ xbf, const UST* __restrict__ WT, const float* __restrict__ bias,
    UST* __restrict__ qext, UST* __restrict__ kext, UST* __restrict__ vT) {
  int m0 = blockIdx.x * 64;   // token tile (4096/64 = 64)
  int n0 = blockIdx.y * 64;   // out-col tile (1536/64 = 24)
  int lane = threadIdx.x & 63, w = threadIdx.x >> 6;
  int g = lane >> 4, c16 = lane & 15;

  int row_a = m0 + w * 16 + c16;
  f32x4 acc[4] = {};
#pragma unroll
  for (int kk = 0; kk < 512; kk += 32) {
    bf16x8 a = *(const bf16x8*)&xbf[(size_t)row_a * 512 + kk + g * 8];
#pragma unroll
    for (int ct = 0; ct < 4; ++ct) {
      int n = n0 + ct * 16 + c16;
      bf16x8 b = *(const bf16x8*)&WT[(size_t)n * 512 + kk + g * 8];
      acc[ct] = __builtin_amdgcn_mfma_f32_16x16x32_bf16(a, b, acc[ct], 0, 0, 0);
    }
  }
  int rowD = m0 + w * 16 + g * 4;
#pragma unroll
  for (int ct = 0; ct < 4; ++ct) {
    int c = n0 + ct * 16 + c16;
    int h = c / 192, rem = c % 192;
    float bv = bias[c];
#pragma unroll
    for (int r = 0; r < 4; ++r) {
      int row = rowD + r;
      int bidx = row >> 10, ltok = row & 1023;
      int bh = bidx * 8 + h;
      UST o = f2bf(acc[ct][r] + bv);
      if (rem < 64)
        qext[((size_t)bh * 1024 + ltok) * 128 + rem] = o;
      else if (rem < 128)
        kext[((size_t)bh * 1024 + ltok) * 128 + (rem - 64)] = o;
      else
        vT[((size_t)bh * 64 + (rem - 128)) * 1024 + ltok] = o;
    }
  }
}

// ---------------- kernel 4: relative-position features (alpha/beta) ----------------
// qext[..][64+j] = q_s*sin(l*d_j)+q_c*cos(l*d_j); qext[..][96+j] = q_c*sin - q_s*cos
// kext[..][64+j] = cos(l*d_j);                    kext[..][96+j] = sin(l*d_j)
__global__ void k_relpos(UST* __restrict__ qext, UST* __restrict__ kext) {
  int gid = blockIdx.x * 256 + threadIdx.x;  // 32*1024*32
  int j = gid & 31;
  int l = (gid >> 5) & 1023;
  int bh = gid >> 15;
  double dd = exp((double)(-2 * j) * (9.210340371976184 / 64.0));
  float ang = (float)l * (float)dd;
  float s = sinf(ang), c = cosf(ang);
  UST* qp = qext + ((size_t)bh * 1024 + l) * 128;
  float qs = bf2f(qp[j]), qc = bf2f(qp[32 + j]);
  qp[64 + j] = f2bf(qs * s + qc * c);
  qp[96 + j] = f2bf(qc * s - qs * c);
  UST* kp = kext + ((size_t)bh * 1024 + l) * 128;
  kp[64 + j] = f2bf(c);
  kp[96 + j] = f2bf(s);
}

// ---------------- kernel 5: fused flash attention ----------------
// grid: 512 blocks = 32 (b,h) x 16 q-tiles of 64 rows; 256 threads = 4 waves,
// each wave owns 16 q-rows independently (no __syncthreads needed).
__global__ __launch_bounds__(256) void k_attn(
    const UST* __restrict__ qext, const UST* __restrict__ kext,
    const UST* __restrict__ vT, float* __restrict__ out) {
  int blk = blockIdx.x;
  int qt = blk & 15, bh = blk >> 4;
  int b = bh >> 3, h = bh & 7;
  int q0 = qt * 64;
  int lane = threadIdx.x & 63, w = threadIdx.x >> 6;
  int g = lane >> 4, c16 = lane & 15;

  __shared__ UST Pl[4][16][72];   // per-wave P tile, padded stride 72 (bank spread)

  // Q fragments: row = q0 + w*16 + c16, k = kf*32 + g*8 .. +7
  const UST* qbase = qext + ((size_t)bh * 1024 + q0 + w * 16 + c16) * 128;
  bf16x8 qf[4];
#pragma unroll
  for (int kf = 0; kf < 4; ++kf) qf[kf] = *(const bf16x8*)&qbase[kf * 32 + g * 8];

  f32x4 O[4] = {};
  float m_r[4] = {-INFINITY, -INFINITY, -INFINITY, -INFINITY};
  float l_r[4] = {0.f, 0.f, 0.f, 0.f};

  for (int k0 = 0; k0 < LSEQ; k0 += 64) {
    // S = Qext * Kext^T  (K=128 contraction: qk + qe fused)
    f32x4 sa[4] = {};
    const UST* kbase = kext + ((size_t)bh * 1024 + k0) * 128;
#pragma unroll
    for (int ct = 0; ct < 4; ++ct) {
      const UST* kb = kbase + (size_t)(ct * 16 + c16) * 128 + g * 8;
#pragma unroll
      for (int kf = 0; kf < 4; ++kf) {
        bf16x8 bf = *(const bf16x8*)&kb[kf * 32];
        sa[ct] = __builtin_amdgcn_mfma_f32_16x16x32_bf16(qf[kf], bf, sa[ct], 0, 0, 0);
      }
    }
    // row max over 64 cols (4 frags x 16-lane group reduce)
    float rmax[4];
#pragma unroll
    for (int r = 0; r < 4; ++r) {
      float v = fmaxf(fmaxf(sa[0][r], sa[1][r]), fmaxf(sa[2][r], sa[3][r]));
      rmax[r] = v;
    }
#pragma unroll
    for (int m = 1; m < 16; m <<= 1)
#pragma unroll
      for (int r = 0; r < 4; ++r) rmax[r] = fmaxf(rmax[r], __shfl_xor(rmax[r], m, 64));

    float ps[4][4], rsum[4], corr[4];
#pragma unroll
    for (int r = 0; r < 4; ++r) {
      float mn = fmaxf(m_r[r], rmax[r] * 0.125f);
      corr[r] = __expf(m_r[r] - mn);   // first iter: exp(-inf)=0
      m_r[r] = mn;
      float sum = 0.f;
#pragma unroll
      for (int ct = 0; ct < 4; ++ct) {
        float p = __expf(sa[ct][r] * 0.125f - mn);
        ps[ct][r] = p;
        sum += p;
      }
      rsum[r] = sum;
    }
#pragma unroll
    for (int m = 1; m < 16; m <<= 1)
#pragma unroll
      for (int r = 0; r < 4; ++r) rsum[r] += __shfl_xor(rsum[r], m, 64);
#pragma unroll
    for (int r = 0; r < 4; ++r) {
      l_r[r] = l_r[r] * corr[r] + rsum[r];
#pragma unroll
      for (int ct = 0; ct < 4; ++ct) O[ct][r] *= corr[r];
    }
    // P -> LDS (bf16), wave-private region
#pragma unroll
    for (int ct = 0; ct < 4; ++ct)
#pragma unroll
      for (int r = 0; r < 4; ++r)
        Pl[w][g * 4 + r][ct * 16 + c16] = f2bf(ps[ct][r]);

    // O += P * V
    const UST* vbase = vT + (size_t)bh * 64 * 1024 + k0;
#pragma unroll
    for (int kf = 0; kf < 2; ++kf) {
      bf16x8 pa = *(const bf16x8*)&Pl[w][c16][kf * 32 + g * 8];
#pragma unroll
      for (int ct = 0; ct < 4; ++ct) {
        bf16x8 vf = *(const bf16x8*)&vbase[(size_t)(ct * 16 + c16) * 1024 + kf * 32 + g * 8];
        O[ct] = __builtin_amdgcn_mfma_f32_16x16x32_bf16(pa, vf, O[ct], 0, 0, 0);
      }
    }
  }

  // epilogue: out[b][row][h*64 + d] = O / l
#pragma unroll
  for (int r = 0; r < 4; ++r) {
    float inv = 1.0f / l_r[r];
    int row = q0 + w * 16 + g * 4 + r;
    float* op = out + ((size_t)b * 1024 + row) * 512 + h * 64;
#pragma unroll
    for (int ct = 0; ct < 4; ++ct) op[ct * 16 + c16] = O[ct][r] * inv;
  }
}

extern "C" void kernel_launch(void* const* d_in, const int* in_sizes, int n_in,
                              void* d_out, int out_size, void* d_ws, size_t ws_size,
                              hipStream_t stream) {
  const float* x = (const float*)d_in[0];
  const float* W = (const float*)d_in[1];
  const float* bias = (const float*)d_in[2];
  float* out = (float*)d_out;

  UST* ws = (UST*)d_ws;
  UST* xbf  = ws;                       // 4096*512
  UST* WT   = xbf + 4096 * 512;         // 1536*512
  UST* qext = WT + 1536 * 512;          // 32*1024*128
  UST* kext = qext + 32 * 1024 * 128;   // 32*1024*128
  UST* vT   = kext + 32 * 1024 * 128;   // 32*64*1024

  k_convert_x<<<dim3(2048), dim3(256), 0, stream>>>(x, xbf);
  k_transpose_W<<<dim3(24, 8), dim3(256), 0, stream>>>(W, WT);
  k_proj<<<dim3(64, 24), dim3(256), 0, stream>>>(xbf, WT, bias, qext, kext, vT);
  k_relpos<<<dim3(4096), dim3(256), 0, stream>>>(qext, kext);
  k_attn<<<dim3(512), dim3(256), 0, stream>>>(qext, kext, vT, out);
}